// Round 7
// baseline (158.770 us; speedup 1.0000x reference)
//
#include <hip/hip_runtime.h>

// ---------------------------------------------------------------------------
// Gate_16501264351574: conv3x3(256ch -> 64 experts) + sigmoid + top8 + softmax
//   x: [16,256,64,64] f32, gate_w: [64,256,3,3] f32, bias: [64] f32
// out (flat f32): weights [16,8,64,64] | indices-as-f32 [16,8,64,64] | counts[64]
//
// R15: two fixes on top of R14 (which broke the plateau: A on lgkmcnt via
// global_load_lds, B on vmcnt, counted-vmcnt barrier; 72.7 -> 55.4 us).
//  (1) LDS bank conflict (counter 2.42M): ds_read start banks were
//      (w*16)%32 in {0,16} -> 16-lane phase on 2 bank groups. Fix = XOR
//      swizzle slot c8 ^= (w>>1)&3 inside each 64B site, applied BOTH
//      sides (rule #21): linear gload_lds dest + inverse-swizzled SOURCE
//      offset in STAGE + swizzled read bases (3 VGPRs, one per kw; the
//      m-tile +1024B offset leaves the swizzle invariant). Start banks
//      now spread across all 32 banks, 2 lanes/bank = free.
//  (2) prep writes were 32B at 64B stride (half-filled). Re-partition:
//      thread = (b,h,q,w): 32 strided channel reads, one 64B contiguous
//      write. Reads stay coalesced.
// Fallback (ws too small): R9 structure verbatim.
// ---------------------------------------------------------------------------

typedef _Float16 half8 __attribute__((ext_vector_type(8)));
typedef __attribute__((ext_vector_type(4))) float f32x4;

#define LOG2E 1.44269504f

__device__ __forceinline__ unsigned short f2h_bits(float f) {
    _Float16 h = (_Float16)f;                  // v_cvt_f16_f32, RNE
    unsigned short b;
    __builtin_memcpy(&b, &h, 2);
    return b;
}

constexpr int WB_U4 = 8 * 9 * 4 * 64;          // 18432 uint4 = 294912 B
constexpr size_t XT_BYTES = (size_t)16 * 66 * 8 * 66 * 32 * 2;  // 35,684,352
constexpr size_t WS_NEED  = XT_BYTES + (size_t)WB_U4 * 16 + 262144;

#define GLOAD16(gp, lp)                                                    \
    __builtin_amdgcn_global_load_lds(                                      \
        (const __attribute__((address_space(1))) void*)(gp),               \
        (__attribute__((address_space(3))) void*)(lp), 16, 0, 0)

// ===========================================================================
// FAST PATH
// ===========================================================================

// prep_all3 roles by blockIdx: [0,2048) interior transpose+cvt (64B writes),
// [2048,2178) border zero, [2178,2250) wB fragments (+counts zero).
constexpr int NB_INT = 2048, NB_BOR = 130, NB_WB = 72;
constexpr int PREP_GRID = NB_INT + NB_BOR + NB_WB;   // 2250

__global__ __launch_bounds__(256) void prep_all3(
    const float* __restrict__ x, const float* __restrict__ gw,
    _Float16* __restrict__ xT, unsigned short* __restrict__ wB,
    float* __restrict__ out) {
    const int blk = blockIdx.x, tid = threadIdx.x;
    if (blk < NB_INT) {
        // interior: thread = (b, h, q, w); 32 channel reads (coalesced along
        // w per j), ONE 64B contiguous write.
        int gid = blk * 256 + tid;
        int w = gid & 63, q = (gid >> 6) & 7, h = (gid >> 9) & 63, b = gid >> 15;
        const float* src = x + (((b * 256 + q * 32) * 64 + h) * 64 + w);
        float v[32];
#pragma unroll
        for (int j = 0; j < 32; ++j) v[j] = src[j * 4096];
        uint4 pk[4];
#pragma unroll
        for (int c8 = 0; c8 < 4; ++c8) {
            pk[c8].x = (unsigned)f2h_bits(v[c8 * 8 + 0]) | ((unsigned)f2h_bits(v[c8 * 8 + 1]) << 16);
            pk[c8].y = (unsigned)f2h_bits(v[c8 * 8 + 2]) | ((unsigned)f2h_bits(v[c8 * 8 + 3]) << 16);
            pk[c8].z = (unsigned)f2h_bits(v[c8 * 8 + 4]) | ((unsigned)f2h_bits(v[c8 * 8 + 5]) << 16);
            pk[c8].w = (unsigned)f2h_bits(v[c8 * 8 + 6]) | ((unsigned)f2h_bits(v[c8 * 8 + 7]) << 16);
        }
        size_t site = ((size_t)(b * 66 + h + 1) * 8 + q) * 66 + (w + 1);
        uint4* dst = (uint4*)xT + site * 4;
        dst[0] = pk[0]; dst[1] = pk[1]; dst[2] = pk[2]; dst[3] = pk[3];
    } else if (blk < NB_INT + NB_BOR) {
        // border zero: 4160 sites x 8 q-slices x 64B; thread zeroes 64B.
        int t = (blk - NB_INT) * 256 + tid;    // < 33280 exactly
        int q = t & 7, site = t >> 3;          // site < 4160
        int sb = site / 260, s = site - sb * 260;
        int hp, wp;
        if (s < 132) { hp = (s >= 66) ? 65 : 0; wp = (s >= 66) ? (s - 66) : s; }
        else         { int s2 = s - 132; hp = 1 + (s2 >> 1); wp = (s2 & 1) * 65; }
        uint4 z = {0u, 0u, 0u, 0u};
        size_t idx = ((((size_t)sb * 66 + hp) * 8 + q) * 66 + wp) * 32;
        uint4* dst = (uint4*)(xT + idx);
#pragma unroll
        for (int k = 0; k < 4; ++k) dst[k] = z;
    } else {
        // wB: chunk-major f16 B-fragments.
        int wblk = blk - (NB_INT + NB_BOR);
        if (wblk == 0 && tid < 64) out[1048576 + tid] = 0.f;
        int g = wblk * 256 + tid;              // < WB_U4 exactly
        int lane = g & 63;
        int nt   = (g >> 6) & 3;
        int rest = g >> 8;                     // q*9 + t
        int t = rest % 9, q = rest / 9;
        int e  = nt * 16 + (lane & 15);
        int c0 = q * 32 + (lane >> 4) * 8;
        unsigned short o[8];
#pragma unroll
        for (int j = 0; j < 8; ++j)
            o[j] = f2h_bits(gw[(e * 256 + c0 + j) * 9 + t]);
        uint4 pk;
        pk.x = (unsigned)o[0] | ((unsigned)o[1] << 16);
        pk.y = (unsigned)o[2] | ((unsigned)o[3] << 16);
        pk.z = (unsigned)o[4] | ((unsigned)o[5] << 16);
        pk.w = (unsigned)o[6] | ((unsigned)o[7] << 16);
        ((uint4*)wB)[g] = pk;
    }
}

// ---------------------------------------------------------------------------
// gate_main4: grid 1024, block = (b=blk&15, r=blk>>4), 4 waves,
// wave = 32pos x 32exp (ph = rw>>1, eh = rw&1).
// LDS: slab dbuf 2 x 12672 B (A chunks), XOR-swizzled; scf aliases slab.
// ---------------------------------------------------------------------------
constexpr int SSTR = 68;                       // fp32 score row stride
constexpr int HALFB = 12672;                   // slab half size (bytes)

__global__ __launch_bounds__(256, 4) void gate_main4(
    const _Float16* __restrict__ xT, const float* __restrict__ bias,
    const unsigned short* __restrict__ wB, float* __restrict__ out) {
    __shared__ uint4 smem4[2 * HALFB / 16];    // 25344 B (scf aliases)
    __shared__ float bias_s[64];
    __shared__ int   hist[64];
    char* smem = (char*)smem4;

    const int tid  = threadIdx.x;
    const int lane = tid & 63;
    const int rw   = tid >> 6;
    const int blk  = blockIdx.x;
    const int b    = blk & 15;
    const int r    = blk >> 4;                 // output row 0..63

    if (tid < 64) { bias_s[tid] = bias[tid]; hist[tid] = 0; }

    const int ph = rw >> 1, eh = rw & 1;

    // ---- staging tasks: 792 granules = 3 segs x 264 x 16B.
    // LDS dest linear (T*16); SOURCE pre-swizzled: o = w*4 + c8 sources
    // from c8 ^ ((w>>1)&3)  [(o>>3)&3 == (w>>1)&3].
    const _Float16* srcP[4];
    int ldsOff[4];
    const bool act3 = (tid < 24);
#pragma unroll
    for (int i = 0; i < 4; ++i) {
        int T = tid + i * 256;
        if (T >= 792) T = 0;                   // inactive (i==3, tid>=24)
        int seg = T / 264, o = T - seg * 264;
        int osrc = (o & ~3) | ((o & 3) ^ ((o >> 3) & 3));
        srcP[i]  = xT + ((size_t)(b * 66 + r + seg) * 8) * 2112 + osrc * 8;
        ldsOff[i] = T * 16;
    }
    auto STAGE = [&](int q, int halfB) {       // 3-4 global_load_lds, 16B each
#pragma unroll
        for (int i = 0; i < 3; ++i)
            GLOAD16(srcP[i] + q * 2112, smem + ldsOff[i] + halfB);
        if (act3)
            GLOAD16(srcP[3] + q * 2112, smem + ldsOff[3] + halfB);
    };

    // ---- A read bases: swizzled slot, one base per kw (m adds +1024B,
    // swizzle invariant: ((w+16)>>1)&3 == (w>>1)&3).
    const int wl = ph * 32 + (lane & 15);
    const char* aB[3];
#pragma unroll
    for (int kw = 0; kw < 3; ++kw) {
        int wp = wl + kw;
        int c8 = (lane >> 4) ^ ((wp >> 1) & 3);
        aB[kw] = smem + wp * 64 + c8 * 16;
    }

    half8 Aa[3][2];
    uint4 Bb[6][2];
    f32x4 acc[2][2];
#pragma unroll
    for (int mt = 0; mt < 2; ++mt)
#pragma unroll
        for (int nt = 0; nt < 2; ++nt) acc[mt][nt] = (f32x4){0.f, 0.f, 0.f, 0.f};

    auto LDA = [&](int kh, int kw, int slot, int HB) {   // all args literal
        Aa[slot][0] = *(const half8*)(aB[kw] + HB + kh * 4224);
        Aa[slot][1] = *(const half8*)(aB[kw] + HB + kh * 4224 + 1024);
    };
    // B: monotonic pointer, +4096B per tap (taps 0..77; tail overreads land
    // in workspace slack, never consumed).
    const char* bP = (const char*)wB + eh * 2048 + lane * 16;
    auto LDB = [&](int slot) {
        Bb[slot][0] = *(const uint4*)bP;
        Bb[slot][1] = *(const uint4*)(bP + 1024);
        bP += 4096;
    };
    auto MT = [&](int as, int bs) {
#pragma unroll
        for (int nt = 0; nt < 2; ++nt) {
            half8 bfr;
            __builtin_memcpy(&bfr, &Bb[bs][nt], 16);
#pragma unroll
            for (int m = 0; m < 2; ++m)
                acc[m][nt] = __builtin_amdgcn_mfma_f32_16x16x32_f16(
                    Aa[as][m], bfr, acc[m][nt], 0, 0, 0);
        }
    };
    auto SB = []() { __builtin_amdgcn_sched_barrier(0); };

    // ---- prologue: stage chunk 0, prefetch B taps 0..5 --------------------
    STAGE(0, 0);
    LDB(0); LDB(1); LDB(2); LDB(3); LDB(4); LDB(5);
    SB();
    asm volatile("s_waitcnt vmcnt(12)" ::: "memory");   // staging(0) landed
    __builtin_amdgcn_s_barrier();
    SB();

    // ---- K loop: 4 x (2 chunks x 9 taps). Counted-vmcnt barrier per chunk.
#pragma unroll 1
    for (int i = 0; i < 4; ++i) {
        // ============ sub-chunk A (q = 2i, reads half 0) ==================
        STAGE(2 * i + 1, HALFB);
        LDA(0, 0, 0, 0); LDA(0, 1, 1, 0); LDA(0, 2, 2, 0);
        SB();
        MT(0, 0); LDA(1, 0, 0, 0); LDB(0); SB();
        MT(1, 1); LDA(1, 1, 1, 0); LDB(1); SB();
        MT(2, 2); LDA(1, 2, 2, 0); LDB(2); SB();
        MT(0, 3); LDA(2, 0, 0, 0); LDB(3); SB();
        MT(1, 4); LDA(2, 1, 1, 0); LDB(4); SB();
        MT(2, 5); LDA(2, 2, 2, 0); LDB(5); SB();
        MT(0, 0); LDB(0); SB();
        MT(1, 1); LDB(1); SB();
        MT(2, 2); LDB(2); SB();
        SB();
        asm volatile("s_waitcnt vmcnt(18) lgkmcnt(0)" ::: "memory");
        __builtin_amdgcn_s_barrier();
        SB();
        // ============ sub-chunk B (q = 2i+1, reads half HALFB) ============
        if (i < 3) STAGE(2 * i + 2, 0);
        LDA(0, 0, 0, HALFB); LDA(0, 1, 1, HALFB); LDA(0, 2, 2, HALFB);
        SB();
        MT(0, 3); LDA(1, 0, 0, HALFB); LDB(3); SB();
        MT(1, 4); LDA(1, 1, 1, HALFB); LDB(4); SB();
        MT(2, 5); LDA(1, 2, 2, HALFB); LDB(5); SB();
        MT(0, 0); LDA(2, 0, 0, HALFB); LDB(0); SB();
        MT(1, 1); LDA(2, 1, 1, HALFB); LDB(1); SB();
        MT(2, 2); LDA(2, 2, 2, HALFB); LDB(2); SB();
        MT(0, 3); LDB(3); SB();
        MT(1, 4); LDB(4); SB();
        MT(2, 5); LDB(5); SB();
        if (i < 3) {
            SB();
            asm volatile("s_waitcnt vmcnt(18) lgkmcnt(0)" ::: "memory");
            __builtin_amdgcn_s_barrier();
            SB();
        }
    }
    __syncthreads();                           // full drain before scf alias

    // ---- epilogue: sigmoid -> fp32 scores in LDS (aliases slab) -----------
    float* scf = (float*)smem4;                // [64][68] f32 = 17408 B
#pragma unroll
    for (int mt = 0; mt < 2; ++mt)
#pragma unroll
        for (int nt = 0; nt < 2; ++nt)
#pragma unroll
            for (int rr = 0; rr < 4; ++rr) {
                float v = acc[mt][nt][rr];
                float s = 1.f / (1.f + __builtin_amdgcn_exp2f(-v * LOG2E));
                int p = ph * 32 + mt * 16 + ((lane >> 4) << 2) + rr;
                int e = eh * 32 + nt * 16 + (lane & 15);
                scf[p * SSTR + e] = s;
            }
    __syncthreads();

    if (tid < 64) {
        const float* row = scf + tid * SSTR;
        float tv[8];
        int   ti[8];
#pragma unroll
        for (int k = 0; k < 8; ++k) { tv[k] = -3.0e38f; ti[k] = 0; }
#pragma unroll
        for (int j4 = 0; j4 < 16; ++j4) {
            f32x4 blkv = *(const f32x4*)(row + j4 * 4);
#pragma unroll
            for (int j = 0; j < 4; ++j) {
                int   e  = j4 * 4 + j;
                float bs = blkv[j] + bias_s[e];
                if (bs > tv[7]) {
                    tv[7] = bs; ti[7] = e;
#pragma unroll
                    for (int k = 7; k > 0; --k) {
                        float fa = tv[k - 1], fb = tv[k];
                        int   ia = ti[k - 1], ib = ti[k];
                        bool  sw = fb > fa;
                        tv[k - 1] = sw ? fb : fa; tv[k] = sw ? fa : fb;
                        ti[k - 1] = sw ? ib : ia; ti[k] = sw ? ia : ib;
                    }
                }
            }
        }
        float u[8], mx = -3.0e38f;
#pragma unroll
        for (int k = 0; k < 8; ++k) { u[k] = tv[k] - bias_s[ti[k]]; mx = fmaxf(mx, u[k]); }
        float ex[8], sum = 0.f;
#pragma unroll
        for (int k = 0; k < 8; ++k) { ex[k] = __builtin_amdgcn_exp2f((u[k] - mx) * LOG2E); sum += ex[k]; }
        float inv = 1.f / sum;

        int obase = b * 32768 + r * 64 + tid;
#pragma unroll
        for (int k = 0; k < 8; ++k) {
            out[obase + k * 4096]          = ex[k] * inv;
            out[524288 + obase + k * 4096] = (float)ti[k];
            atomicAdd(&hist[ti[k]], 1);
        }
    }
    __syncthreads();
    if (tid < 64) atomicAdd(out + 1048576 + tid, (float)hist[tid]);
}

// ===========================================================================
// FALLBACK PATH (R9 verbatim)
// ===========================================================================

__global__ __launch_bounds__(256) void gate_prep(const float* __restrict__ gw,
                                                 unsigned short* __restrict__ wB,
                                                 float* __restrict__ out) {
    int g = blockIdx.x * 256 + threadIdx.x;
    if (blockIdx.x == 0 && threadIdx.x < 64) out[1048576 + threadIdx.x] = 0.f;
    if (g >= WB_U4) return;
    int lane = g & 63;
    int nt   = (g >> 6) & 3;
    int rest = g >> 8;
    int t = rest % 9, q = rest / 9;
    int e  = nt * 16 + (lane & 15);
    int c0 = q * 32 + (lane >> 4) * 8;
    unsigned short o[8];
#pragma unroll
    for (int j = 0; j < 8; ++j)
        o[j] = f2h_bits(gw[(e * 256 + c0 + j) * 9 + t]);
    uint4 pk;
    pk.x = (unsigned)o[0] | ((unsigned)o[1] << 16);
    pk.y = (unsigned)o[2] | ((unsigned)o[3] << 16);
    pk.z = (unsigned)o[4] | ((unsigned)o[5] << 16);
    pk.w = (unsigned)o[6] | ((unsigned)o[7] << 16);
    ((uint4*)wB)[g] = pk;
}

constexpr int CSTR = 40;
constexpr int SLAB = 3 * 66 * CSTR;

__global__ __launch_bounds__(256, 4) void gate_main_fb(
    const float* __restrict__ x, const float* __restrict__ bias,
    const unsigned short* __restrict__ wB, float* __restrict__ out) {
    __shared__ unsigned short xs[2 * SLAB];
    __shared__ float bias_s[64];
    __shared__ int   hist[64];

    const int tid  = threadIdx.x;
    const int lane = tid & 63;
    const int rw   = tid >> 6;
    const int blk  = blockIdx.x;
    const int b    = blk & 15;
    const int r    = blk >> 4;

    if (tid < 64) { bias_s[tid] = bias[tid]; hist[tid] = 0; }
    {
        uint4 z = {0u, 0u, 0u, 0u};
        uint4* p = (uint4*)xs;
#pragma unroll
        for (int i = 0; i < 8; ++i) {
            int idx = tid + i * 256;
            if (idx < 2 * SLAB / 8) p[idx] = z;
        }
    }

    bool tOk[4];
    int  tSrc[4], tDst[4];
#pragma unroll
    for (int i = 0; i < 4; ++i) {
        int T = tid + i * 256;
        bool ex = (T < 792);
        int chh = T / 198, s = T - chh * 198;
        int row2 = s / 66, wp = s - row2 * 66;
        int gr = r - 1 + row2, gwc = wp - 1;
        tOk[i]  = ex && (gr >= 0) && (gr < 64) && (gwc >= 0) && (gwc < 64);
        tSrc[i] = ((b * 256 + chh * 8) * 64 + gr) * 64 + gwc;
        tDst[i] = (row2 * 66 + wp) * CSTR + chh * 8;
    }

    float tb[4][8];
    auto issueT = [&](int i, int dq) {
        if (tOk[i]) {
            const float* p = x + tSrc[i] + dq * 131072;
#pragma unroll
            for (int u = 0; u < 8; ++u) tb[i][u] = p[u * 4096];
        }
    };
    auto commitT = [&](int i, unsigned short* dst) {
        if (tOk[i]) {
            uint4 pk;
            pk.x = (unsigned)f2h_bits(tb[i][0]) | ((unsigned)f2h_bits(tb[i][1]) << 16);
            pk.y = (unsigned)f2h_bits(tb[i][2]) | ((unsigned)f2h_bits(tb[i][3]) << 16);
            pk.z = (unsigned)f2h_bits(tb[i][4]) | ((unsigned)f2h_bits(tb[i][5]) << 16);
            pk.w = (unsigned)f2h_bits(tb[i][6]) | ((unsigned)f2h_bits(tb[i][7]) << 16);
            *(uint4*)(dst + tDst[i]) = pk;
        }
    };

    const int ph = rw >> 1, eh = rw & 1;
    half8 Aa[3][2];
    uint4 Bb[3][2];
    auto prefA = [&](const unsigned short* buf, int t, int slot) {
        const int kh = t / 3, kw = t % 3;
        const unsigned short* abase =
            buf + (kh * 66 + ph * 32 + (lane & 15) + kw) * CSTR + (lane >> 4) * 8;
#pragma unroll
        for (int mt = 0; mt < 2; ++mt)
            Aa[slot][mt] = *(const half8*)(abase + mt * 16 * CSTR);
    };
    auto prefB = [&](int T9, int slot) {
        const uint4* bp = (const uint4*)wB + (T9 * 4 + eh * 2) * 64 + lane;
#pragma unroll
        for (int nt = 0; nt < 2; ++nt) Bb[slot][nt] = bp[nt * 64];
    };

    f32x4 acc[2][2];
#pragma unroll
    for (int mt = 0; mt < 2; ++mt)
#pragma unroll
        for (int nt = 0; nt < 2; ++nt) acc[mt][nt] = (f32x4){0.f, 0.f, 0.f, 0.f};

    auto mfma_tap = [&](int slot) {
#pragma unroll
        for (int nt = 0; nt < 2; ++nt) {
            half8 bfr;
            __builtin_memcpy(&bfr, &Bb[slot][nt], 16);
#pragma unroll
            for (int mt = 0; mt < 2; ++mt)
                acc[mt][nt] = __builtin_amdgcn_mfma_f32_16x16x32_f16(
                    Aa[slot][mt], bfr, acc[mt][nt], 0, 0, 0);
        }
    };

    __syncthreads();
    issueT(0, 0); issueT(1, 0); issueT(2, 0); issueT(3, 0);
    commitT(0, xs); commitT(1, xs); commitT(2, xs); commitT(3, xs);
    issueT(0, 1); issueT(1, 1); issueT(2, 1); issueT(3, 1);
    prefB(0, 0); prefB(1, 1); prefB(2, 2);
    __syncthreads();

#pragma unroll 1
    for (int q = 0; q < 8; ++q) {
        const unsigned short* cur = xs + (q & 1) * SLAB;
        unsigned short*       nxt = xs + ((q + 1) & 1) * SLAB;
        const int  T0  = q * 9;
        const bool cmt = (q < 7);
        const bool iss = (q < 6);

        prefA(cur, 0, 0); prefA(cur, 1, 1);
        mfma_tap(0); prefB(T0 + 3, 0); prefA(cur, 2, 2);
        mfma_tap(1); prefB(T0 + 4, 1); prefA(cur, 3, 0);
        if (cmt) { commitT(0, nxt); commitT(1, nxt); }
        mfma_tap(2); prefB(T0 + 5, 2); prefA(cur, 4, 1);
        mfma_tap(0); prefB(T0 + 6, 0); prefA(cur, 5, 2);
        if (cmt) { commitT(2, nxt); commitT(3, nxt); }
        mfma_tap(1); prefB(T0 + 7, 1); prefA(cur, 6, 0);
        mfma_tap(2); prefB(T0 + 8, 2); prefA(cur, 7, 1);
        __builtin_amdgcn_sched_barrier(0);
        if (iss) { issueT(0, q + 2); issueT(1, q + 2); issueT(2, q + 2); issueT(3, q + 2); }
        __builtin_amdgcn_sched_barrier(0);
        mfma_tap(0); if (cmt) prefB(T0 + 9, 0);  prefA(cur, 8, 2);
        mfma_tap(1); if (cmt) prefB(T0 + 10, 1);
        mfma_tap(2); if (cmt) prefB(T0 + 11, 2);
        __syncthreads();
    }

    float* scf2 = (float*)xs;
#pragma unroll
    for (int mt = 0; mt < 2; ++mt)
#pragma unroll
        for (int nt = 0; nt < 2; ++nt)
#pragma unroll
            for (int rr = 0; rr < 4; ++rr) {
                float v = acc[mt][nt][rr];
                float s = 1.f / (1.f + __builtin_amdgcn_exp2f(-v * LOG2E));
                int p = ph * 32 + mt * 16 + ((lane >> 4) << 2) + rr;
                int e = eh * 32 + nt * 16 + (lane & 15);
                scf2[p * SSTR + e] = s;
            }
    __syncthreads();

    if (tid < 64) {
        const float* row = scf2 + tid * SSTR;
        float tv[8];
        int   ti[8];
#pragma unroll
        for (int k = 0; k < 8; ++k) { tv[k] = -3.0e38f; ti[k] = 0; }
#pragma unroll
        for (int j4 = 0; j4 < 16; ++j4) {
            f32x4 blkv = *(const f32x4*)(row + j4 * 4);
#pragma unroll
            for (int j = 0; j < 4; ++j) {
                int   e  = j4 * 4 + j;
                float bs = blkv[j] + bias_s[e];
                if (bs > tv[7]) {
                    tv[7] = bs; ti[7] = e;
#pragma unroll
                    for (int k = 7; k > 0; --k) {
                        float fa = tv[k - 1], fb = tv[k];
                        int   ia = ti[k - 1], ib = ti[k];
                        bool  sw = fb > fa;
                        tv[k - 1] = sw ? fb : fa; tv[k] = sw ? fa : fb;
                        ti[k - 1] = sw ? ib : ia; ti[k] = sw ? ia : ib;
                    }
                }
            }
        }
        float u[8], mx = -3.0e38f;
#pragma unroll
        for (int k = 0; k < 8; ++k) { u[k] = tv[k] - bias_s[ti[k]]; mx = fmaxf(mx, u[k]); }
        float ex[8], sum = 0.f;
#pragma unroll
        for (int k = 0; k < 8; ++k) { ex[k] = __builtin_amdgcn_exp2f((u[k] - mx) * LOG2E); sum += ex[k]; }
        float inv = 1.f / sum;

        int obase = b * 32768 + r * 64 + tid;
#pragma unroll
        for (int k = 0; k < 8; ++k) {
            out[obase + k * 4096]          = ex[k] * inv;
            out[524288 + obase + k * 4096] = (float)ti[k];
            atomicAdd(&hist[ti[k]], 1);
        }
    }
    __syncthreads();
    if (tid < 64) atomicAdd(out + 1048576 + tid, (float)hist[tid]);
}

// ---------------------------------------------------------------------------
extern "C" void kernel_launch(void* const* d_in, const int* in_sizes, int n_in,
                              void* d_out, int out_size, void* d_ws, size_t ws_size,
                              hipStream_t stream) {
    const float* x    = (const float*)d_in[0];
    const float* gw   = (const float*)d_in[1];
    const float* bias = (const float*)d_in[2];
    float* out = (float*)d_out;

    if (ws_size >= WS_NEED) {
        _Float16* xT = (_Float16*)d_ws;
        unsigned short* wB = (unsigned short*)((char*)d_ws + XT_BYTES);
        prep_all3<<<PREP_GRID, 256, 0, stream>>>(x, gw, xT, wB, out);
        gate_main4<<<1024, 256, 0, stream>>>(xT, bias, wB, out);
    } else {
        unsigned short* wB = (unsigned short*)d_ws;
        gate_prep<<<72, 256, 0, stream>>>(gw, wB, out);
        gate_main_fb<<<1024, 256, 0, stream>>>(x, bias, wB, out);
    }
}